// Round 1
// 1342.583 us; speedup vs baseline: 1.0855x; 1.0855x over previous
//
#include <hip/hip_runtime.h>
#include <hip/hip_bf16.h>

#define N_USERS 50000
#define N_ITEMS 4000
#define BATCH   256
#define KSTEPS  125            // 4000 / 32
#define NWG     391            // ceil(50000 / 128)
#define NEG_INF (-3.402823466e38f)

typedef __attribute__((ext_vector_type(8)))  __bf16 bfrag;
typedef __attribute__((ext_vector_type(16))) float  f32x16;

__device__ __forceinline__ unsigned short f2bf(float f) {
  unsigned u = __float_as_uint(f);
  return (unsigned short)((u + 0x7FFFu + ((u >> 16) & 1u)) >> 16);  // RNE
}

// ---------------- Kernel 1: gather user rows, convert bf16, pack directly in
// MFMA A-fragment lane order so gemm loads frags from L2 with no LDS round-trip.
// Lane l of frag f at kstep ks, sub-k s reads A[f*32 + (l&31)][ks*32 + s*16 + (l>>5)*8 + e].
// ushort idx = ((kk>>4)*8 + (m>>5))*512 + ((m&31) + 32*((kk>>3)&1))*8 + (kk&7)
__global__ __launch_bounds__(256) void prep_pack(
    const float* __restrict__ F, const int* __restrict__ uids,
    unsigned short* __restrict__ apack) {
  int m = blockIdx.x;
  const int f = m >> 5, lr = m & 31;
  size_t base = (size_t)uids[m] * N_ITEMS;
  for (int kk = threadIdx.x * 4; kk < N_ITEMS; kk += 1024) {
    float4 v = *(const float4*)(F + base + kk);
    ushort4 o;
    o.x = f2bf(v.x); o.y = f2bf(v.y); o.z = f2bf(v.z); o.w = f2bf(v.w);
    int idx = ((kk >> 4) * 8 + f) * 512 + (lr + ((kk >> 3) & 1) * 32) * 8 + (kk & 7);
    *(ushort4*)(apack + idx) = o;
  }
}

// ---------------- Kernel 2: fused GEMM (256x128 tile) + norm_all + per-WG top-8 per row
// Wave mapping: mh = w>>1 owns m-frags {4mh..4mh+3}, nh = w&1 owns n-frags {2nh,2nh+1}.
// A-frags direct from L2 (prepacked); B double-buffered in LDS, one barrier per kstep,
// 2-deep register prefetch of B (issued AFTER A loads so vmcnt waits don't drain it).
__global__ __launch_bounds__(256, 2) void gemm_topk(
    const float* __restrict__ F, const unsigned short* __restrict__ apack,
    float2* __restrict__ wstop) {
  union Smem {
    unsigned short Bs[2][128][40];   // 40: odd-granule (80B) stride -> conflict-free b128
    float dump[256][33];
  };
  __shared__ Smem sm;
  __shared__ float norms[128];

  const int tid   = threadIdx.x;
  const int w     = tid >> 6, lane = tid & 63;
  const int lrow  = lane & 31, lhalf = lane >> 5;
  const int mh    = w >> 1, nh = w & 1;
  const int n0    = blockIdx.x * 128;

  // B staging assignment: row = tid>>1, half = tid&1 (16 floats each)
  const int brow = tid >> 1, bh = tid & 1;
  int grow = n0 + brow; if (grow >= N_USERS) grow = 0;   // clamp: finite garbage, masked later
  const float4* bptr = (const float4*)(F + (size_t)grow * N_ITEMS) + bh * 4;
  const unsigned short* abase = apack + (mh * 4) * 512 + lane * 8;

  f32x16 acc[4][2];
  #pragma unroll
  for (int i = 0; i < 4; ++i)
    #pragma unroll
    for (int j = 0; j < 2; ++j)
      #pragma unroll
      for (int e = 0; e < 16; ++e) acc[i][j][e] = 0.f;

  float ssq = 0.f;
  float4 brA[4], brB[4];

#define LOADB(SET, T) do { \
    const float4* bp_ = bptr + (T) * 8; \
    _Pragma("unroll") for (int q_ = 0; q_ < 4; ++q_) SET[q_] = bp_[q_]; \
  } while (0)

#define CONVW(SET, BUF) do { \
    const float* vv_ = (const float*)SET; \
    union { unsigned short s[8]; uint4 v; } h0_, h1_; \
    _Pragma("unroll") for (int e_ = 0; e_ < 8; ++e_) h0_.s[e_] = f2bf(vv_[e_]); \
    _Pragma("unroll") for (int e_ = 0; e_ < 8; ++e_) h1_.s[e_] = f2bf(vv_[8 + e_]); \
    _Pragma("unroll") for (int e_ = 0; e_ < 16; ++e_) ssq = fmaf(vv_[e_], vv_[e_], ssq); \
    *(uint4*)&sm.Bs[BUF][brow][bh * 16]     = h0_.v; \
    *(uint4*)&sm.Bs[BUF][brow][bh * 16 + 8] = h1_.v; \
  } while (0)

  // Per kstep: [A loads (L2)] [B global prefetch t+2] happen around the MFMA block;
  // conversion of t+1 -> Bs[PAR^1] overlaps; single __syncthreads per kstep.
#define STEP(T, CSET, LSET, PAR) do { \
    _Pragma("unroll") for (int s_ = 0; s_ < 2; ++s_) { \
      bfrag av_[4], bf_[2]; \
      _Pragma("unroll") for (int i_ = 0; i_ < 4; ++i_) \
        av_[i_] = *(const bfrag*)(abase + (T) * 8192 + s_ * 4096 + i_ * 512); \
      _Pragma("unroll") for (int jj_ = 0; jj_ < 2; ++jj_) \
        bf_[jj_] = *(const bfrag*)&sm.Bs[PAR][(2 * nh + jj_) * 32 + lrow][s_ * 16 + lhalf * 8]; \
      _Pragma("unroll") for (int i_ = 0; i_ < 4; ++i_) \
        _Pragma("unroll") for (int jj_ = 0; jj_ < 2; ++jj_) \
          acc[i_][jj_] = __builtin_amdgcn_mfma_f32_32x32x16_bf16(av_[i_], bf_[jj_], acc[i_][jj_], 0, 0, 0); \
    } \
    if ((T) + 2 < KSTEPS) LOADB(LSET, (T) + 2); \
    if ((T) + 1 < KSTEPS) CONVW(CSET, (PAR) ^ 1); \
    __syncthreads(); \
  } while (0)

  // prologue: kstep 0 staged, kstep 1 in regs
  LOADB(brA, 0);
  LOADB(brB, 1);
  CONVW(brA, 0);
  __syncthreads();

  for (int t = 0; t < KSTEPS - 1; t += 2) {
    STEP(t,     brB, brA, 0);   // compute ks t   (buf0), convert ks t+1 -> buf1, load ks t+2
    STEP(t + 1, brA, brB, 1);   // compute ks t+1 (buf1), convert ks t+2 -> buf0, load ks t+3
  }
  STEP(KSTEPS - 1, brB, brA, 0);  // ks 124 (even parity); conv/load guards are false

#undef STEP
#undef CONVW
#undef LOADB

  // norm_all for this WG's 128 columns (pair-reduce the two half-rows)
  ssq += __shfl_xor(ssq, 1);
  if (bh == 0) norms[brow] = fmaxf(ssq, 1e-8f);

  // per-row approx top-8 over this WG's 128 columns (4 passes, one n-frag each)
  float tv[8]; int ti[8];
  #pragma unroll
  for (int q = 0; q < 8; ++q) { tv[q] = NEG_INF; ti[q] = 0; }

  #pragma unroll
  for (int p = 0; p < 4; ++p) {
    __syncthreads();   // p==0: also guarantees MFMA LDS reads done + norms visible
    if (nh == (p >> 1)) {
      const int jj  = p & 1;
      const int ugc = n0 + 32 * p + lrow;
      const float inv = 1.0f / norms[32 * p + lrow];
      #pragma unroll
      for (int i = 0; i < 4; ++i)
        #pragma unroll
        for (int r = 0; r < 16; ++r) {
          int mrow = 128 * mh + 32 * i + (r & 3) + 8 * (r >> 2) + 4 * lhalf;  // verified C/D map
          sm.dump[mrow][lrow] = (ugc < N_USERS) ? acc[i][jj][r] * inv : NEG_INF;
        }
    }
    __syncthreads();
    for (int c = 0; c < 32; ++c) {
      float v = sm.dump[tid][c];
      int ci = n0 + 32 * p + c;
      if (v > tv[7]) {
        #pragma unroll
        for (int q = 0; q < 8; ++q) {
          bool gt = v > tv[q];
          float ov = tv[q]; int oi = ti[q];
          tv[q] = gt ? v : ov; ti[q] = gt ? ci : oi;
          v = gt ? ov : v;     ci = gt ? oi : ci;
        }
      }
    }
  }

  float2* dst = wstop + ((size_t)blockIdx.x * 256 + tid) * 8;   // b-row == tid
  #pragma unroll
  for (int q = 0; q < 8; ++q) dst[q] = make_float2(tv[q], __int_as_float(ti[q]));
}

// ---------------- Kernel 3: merge 391x8 candidates -> top-32 per row
__global__ __launch_bounds__(64) void merge_topk(
    const float2* __restrict__ wstop, int* __restrict__ cand) {
  const int b = blockIdx.x, l = threadIdx.x;
  float tv[8]; int ti[8];
  #pragma unroll
  for (int q = 0; q < 8; ++q) { tv[q] = NEG_INF; ti[q] = 0; }
  for (int c = l; c < NWG * 8; c += 64) {
    int wg = c >> 3, q = c & 7;
    float2 e = wstop[((size_t)wg * 256 + b) * 8 + q];
    float v = e.x; int ci = __float_as_int(e.y);
    #pragma unroll
    for (int q2 = 0; q2 < 8; ++q2) {
      bool gt = v > tv[q2];
      float ov = tv[q2]; int oi = ti[q2];
      tv[q2] = gt ? v : ov; ti[q2] = gt ? ci : oi;
      v = gt ? ov : v;      ci = gt ? oi : ci;
    }
  }
  __shared__ float sv[512];
  __shared__ int   si[512];
  #pragma unroll
  for (int q = 0; q < 8; ++q) { sv[l * 8 + q] = tv[q]; si[l * 8 + q] = ti[q]; }
  __syncthreads();
  if (l == 0) {
    float bv[32]; int bi[32];
    #pragma unroll
    for (int q = 0; q < 32; ++q) { bv[q] = NEG_INF; bi[q] = 0; }
    for (int n = 0; n < 512; ++n) {
      float v = sv[n];
      if (v > bv[31]) {
        int ci = si[n];
        #pragma unroll
        for (int q = 0; q < 32; ++q) {
          bool gt = v > bv[q];
          float ov = bv[q]; int oi = bi[q];
          bv[q] = gt ? v : ov; bi[q] = gt ? ci : oi;
          v = gt ? ov : v;     ci = gt ? oi : ci;
        }
      }
    }
    #pragma unroll
    for (int q = 0; q < 32; ++q) cand[b * 32 + q] = bi[q];
  }
}

// ---------------- Kernel 4: exact fp64 rescore of the 32 candidates per row
__global__ __launch_bounds__(64) void rescore(
    const float* __restrict__ F, const int* __restrict__ uids,
    const int* __restrict__ cand, double* __restrict__ simx) {
  const int pr = blockIdx.x;           // b*32 + q
  const int b  = pr >> 5;
  const int ci = cand[pr];
  const float* fa = F + (size_t)uids[b] * N_ITEMS;
  const float* fc = F + (size_t)ci * N_ITEMS;
  double dot = 0.0, ss = 0.0;
  for (int k = threadIdx.x * 4; k < N_ITEMS; k += 256) {
    float4 a = *(const float4*)(fa + k);
    float4 c = *(const float4*)(fc + k);
    dot += (double)a.x * c.x + (double)a.y * c.y + (double)a.z * c.z + (double)a.w * c.w;
    ss  += (double)c.x * c.x + (double)c.y * c.y + (double)c.z * c.z + (double)c.w * c.w;
  }
  #pragma unroll
  for (int off = 32; off > 0; off >>= 1) {
    dot += __shfl_down(dot, off);
    ss  += __shfl_down(ss, off);
  }
  // norm_users cancels in the weight normalization -> rank/weight by dot/norm_all only
  if (threadIdx.x == 0) simx[pr] = dot / fmax(ss, 1e-8);
}

// ---------------- Kernel 5: exact top-10, weights, weighted neighbor sum
__global__ __launch_bounds__(256) void finalize(
    const float* __restrict__ F, const int* __restrict__ cand,
    const double* __restrict__ simx, float* __restrict__ out) {
  const int b = blockIdx.x;
  __shared__ float wsh[10];
  __shared__ int   ish[10];
  if (threadIdx.x == 0) {
    double bv[10]; int bi[10];
    #pragma unroll
    for (int q = 0; q < 10; ++q) { bv[q] = -1.0e300; bi[q] = 0; }
    for (int n = 0; n < 32; ++n) {
      double v = simx[b * 32 + n];
      int ci = cand[b * 32 + n];
      #pragma unroll
      for (int q = 0; q < 10; ++q) {
        bool gt = v > bv[q];
        double ov = bv[q]; int oi = bi[q];
        bv[q] = gt ? v : ov; bi[q] = gt ? ci : oi;
        v = gt ? ov : v;     ci = gt ? oi : ci;
      }
    }
    double s = 0.0;
    #pragma unroll
    for (int q = 0; q < 10; ++q) s += bv[q];
    #pragma unroll
    for (int q = 0; q < 10; ++q) { wsh[q] = (float)(bv[q] / s); ish[q] = bi[q]; }
  }
  __syncthreads();
  float wr[10]; size_t ro[10];
  #pragma unroll
  for (int q = 0; q < 10; ++q) { wr[q] = wsh[q]; ro[q] = (size_t)ish[q] * N_ITEMS; }
  for (int i = threadIdx.x; i < N_ITEMS; i += 256) {
    float a = 0.f;
    #pragma unroll
    for (int q = 0; q < 10; ++q) a = fmaf(wr[q], F[ro[q] + i], a);
    out[b * N_ITEMS + i] = a;
  }
}

extern "C" void kernel_launch(void* const* d_in, const int* in_sizes, int n_in,
                              void* d_out, int out_size, void* d_ws, size_t ws_size,
                              hipStream_t stream) {
  const float* F    = (const float*)d_in[0];
  const int*   uids = (const int*)d_in[1];   // num_neighbors (d_in[2]) is fixed at 10
  float* out = (float*)d_out;
  char*  ws  = (char*)d_ws;

  // workspace layout (~8.6 MB total)
  unsigned short* apack = (unsigned short*)ws;                       // 2,048,000 B
  float2* wstop = (float2*)(ws + 2097152);                           // 6,406,144 B
  int*    cand  = (int*)(ws + 2097152 + 6406144);                    //    32,768 B
  double* simx  = (double*)(ws + 2097152 + 6406144 + 32768);         //    65,536 B

  prep_pack<<<dim3(BATCH), dim3(256), 0, stream>>>(F, uids, apack);
  gemm_topk<<<dim3(NWG),   dim3(256), 0, stream>>>(F, apack, wstop);
  merge_topk<<<dim3(BATCH), dim3(64), 0, stream>>>(wstop, cand);
  rescore<<<dim3(BATCH * 32), dim3(64), 0, stream>>>(F, uids, cand, simx);
  finalize<<<dim3(BATCH), dim3(256), 0, stream>>>(F, cand, simx, out);
}

// Round 2
// 1290.499 us; speedup vs baseline: 1.1293x; 1.0404x over previous
//
#include <hip/hip_runtime.h>
#include <hip/hip_bf16.h>

#define N_USERS 50000
#define N_ITEMS 4000
#define BATCH   256
#define KSTEPS  125            // 4000 / 32
#define NWG     391            // ceil(50000 / 128)
#define NEG_INF (-3.402823466e38f)

typedef __attribute__((ext_vector_type(8)))  __bf16 bfrag;
typedef __attribute__((ext_vector_type(16))) float  f32x16;

__device__ __forceinline__ unsigned short f2bf(float f) {
  unsigned u = __float_as_uint(f);
  return (unsigned short)((u + 0x7FFFu + ((u >> 16) & 1u)) >> 16);  // RNE
}

// ---------------- Kernel 1: gather user rows, convert bf16, pack directly in
// MFMA A-fragment lane order so gemm loads frags from L2 with no LDS round-trip.
// Lane l of frag f at kstep ks, sub-k s reads A[f*32 + (l&31)][ks*32 + s*16 + (l>>5)*8 + e].
// ushort idx = ((kk>>4)*8 + (m>>5))*512 + ((m&31) + 32*((kk>>3)&1))*8 + (kk&7)
__global__ __launch_bounds__(256) void prep_pack(
    const float* __restrict__ F, const int* __restrict__ uids,
    unsigned short* __restrict__ apack) {
  int m = blockIdx.x;
  const int f = m >> 5, lr = m & 31;
  size_t base = (size_t)uids[m] * N_ITEMS;
  for (int kk = threadIdx.x * 4; kk < N_ITEMS; kk += 1024) {
    float4 v = *(const float4*)(F + base + kk);
    ushort4 o;
    o.x = f2bf(v.x); o.y = f2bf(v.y); o.z = f2bf(v.z); o.w = f2bf(v.w);
    int idx = ((kk >> 4) * 8 + f) * 512 + (lr + ((kk >> 3) & 1) * 32) * 8 + (kk & 7);
    *(ushort4*)(apack + idx) = o;
  }
}

// ---------------- Kernel 2: fused GEMM (256x128 tile) + norm_all + per-WG top-8 per row
// 4 waves: mh = w>>1 owns m-frags {4mh..4mh+3}, nh = w&1 owns n-frags {2nh,2nh+1}.
// A-frags direct from L2 (prepacked), register double-buffered (avA/avB).
// B double-buffered in LDS with XOR swizzle (byte ^= (row&7)<<4), reg-staged 2 deep.
// RAW s_barrier + lgkmcnt(0) only: global loads stay in flight across barriers;
// compiler emits counted vmcnt waits (A issued before B each step so A releases first).
__global__ __launch_bounds__(256, 2) void gemm_topk(
    const float* __restrict__ F, const unsigned short* __restrict__ apack,
    float2* __restrict__ wstop) {
  union Smem {
    unsigned short Bs[2][128][32];   // linear 64 B rows + XOR swizzle on both sides
    float dump[256][33];
  };
  __shared__ Smem sm;
  __shared__ float norms[128];

  const int tid   = threadIdx.x;
  const int w     = tid >> 6, lane = tid & 63;
  const int lrow  = lane & 31, lhalf = lane >> 5;
  const int mh    = w >> 1, nh = w & 1;
  const int n0    = blockIdx.x * 128;

  // B staging assignment: row = tid>>1, half = tid&1 (16 floats each)
  const int brow = tid >> 1, bh = tid & 1;
  int grow = n0 + brow; if (grow >= N_USERS) grow = 0;   // clamp: finite garbage, masked later
  const float4* bptr = (const float4*)(F + (size_t)grow * N_ITEMS) + bh * 4;
  const unsigned short* abase = apack + (mh * 4) * 512 + lane * 8;

  unsigned short* bsbase = &sm.Bs[0][0][0];

  // precomputed swizzled LDS byte offsets (write side)
  const unsigned wsw   = ((unsigned)(brow & 7)) << 4;
  const unsigned woff0 = ((unsigned)(brow * 64 + bh * 32))      ^ wsw;
  const unsigned woff1 = ((unsigned)(brow * 64 + bh * 32 + 16)) ^ wsw;

  // precomputed swizzled LDS byte offsets (read side): R = (2nh+jj)*32 + lrow
  unsigned roff[2][2];
  #pragma unroll
  for (int jj = 0; jj < 2; ++jj) {
    int R = (2 * nh + jj) * 32 + lrow;
    unsigned sw = ((unsigned)(R & 7)) << 4;
    #pragma unroll
    for (int s = 0; s < 2; ++s)
      roff[jj][s] = ((unsigned)(R * 64 + s * 32 + lhalf * 16)) ^ sw;
  }

  f32x16 acc[4][2];
  #pragma unroll
  for (int i = 0; i < 4; ++i)
    #pragma unroll
    for (int j = 0; j < 2; ++j)
      #pragma unroll
      for (int e = 0; e < 16; ++e) acc[i][j][e] = 0.f;

  float ssq = 0.f;
  float4 brA[4], brB[4];
  bfrag  avA[8], avB[8];

#define LOADA(AV, T) do { \
    _Pragma("unroll") for (int s_ = 0; s_ < 2; ++s_) \
      _Pragma("unroll") for (int i_ = 0; i_ < 4; ++i_) \
        AV[s_ * 4 + i_] = *(const bfrag*)(abase + (size_t)(T) * 8192 + s_ * 4096 + i_ * 512); \
  } while (0)

#define LOADB(SET, T) do { \
    const float4* bp_ = bptr + (T) * 8; \
    _Pragma("unroll") for (int q_ = 0; q_ < 4; ++q_) SET[q_] = bp_[q_]; \
  } while (0)

#define CONVW(SET, PAR) do { \
    const float* vv_ = (const float*)SET; \
    union { unsigned short s_[8]; uint4 v_; } h0_, h1_; \
    _Pragma("unroll") for (int e_ = 0; e_ < 8; ++e_) h0_.s_[e_] = f2bf(vv_[e_]); \
    _Pragma("unroll") for (int e_ = 0; e_ < 8; ++e_) h1_.s_[e_] = f2bf(vv_[8 + e_]); \
    _Pragma("unroll") for (int e_ = 0; e_ < 16; ++e_) ssq = fmaf(vv_[e_], vv_[e_], ssq); \
    char* wb_ = (char*)bsbase + (PAR) * 16384; \
    *(uint4*)(wb_ + woff0) = h0_.v_; \
    *(uint4*)(wb_ + woff1) = h1_.v_; \
  } while (0)

#define MFMA_STEP(AV, PAR) do { \
    _Pragma("unroll") for (int s_ = 0; s_ < 2; ++s_) { \
      bfrag bf_[2]; \
      _Pragma("unroll") for (int jj_ = 0; jj_ < 2; ++jj_) \
        bf_[jj_] = *(const bfrag*)((char*)bsbase + (PAR) * 16384 + roff[jj_][s_]); \
      _Pragma("unroll") for (int i_ = 0; i_ < 4; ++i_) \
        _Pragma("unroll") for (int jj_ = 0; jj_ < 2; ++jj_) \
          acc[i_][jj_] = __builtin_amdgcn_mfma_f32_32x32x16_bf16(AV[s_ * 4 + i_], bf_[jj_], acc[i_][jj_], 0, 0, 0); \
    } \
  } while (0)

  // Raw barrier: drains LDS (lgkmcnt) for cross-wave visibility but leaves the
  // global loads (vmcnt) in flight — the whole point of this schedule.
#define KBARRIER() do { \
    asm volatile("s_waitcnt lgkmcnt(0)" ::: "memory"); \
    __builtin_amdgcn_s_barrier(); \
  } while (0)

  // One kstep. VMEM issue order matters: A(T+1) BEFORE B(T+2), so next step's
  // MFMA wait (vmcnt(4)) releases A while leaving B in flight, and CONVW's wait
  // (vmcnt(12)) releases B(T+1) while leaving A(T+2)+B(T+3) in flight.
#define STEP(T, AVCUR, AVNXT, CSET, LSET, PAR) do { \
    MFMA_STEP(AVCUR, PAR); \
    if ((T) + 1 < KSTEPS) LOADA(AVNXT, (T) + 1); \
    if ((T) + 2 < KSTEPS) LOADB(LSET, (T) + 2); \
    if ((T) + 1 < KSTEPS) CONVW(CSET, (PAR) ^ 1); \
    KBARRIER(); \
  } while (0)

  // prologue: A(0) in avA, B(0) converted into Bs[0], B(1) in brB regs
  LOADA(avA, 0);
  LOADB(brA, 0);
  LOADB(brB, 1);
  CONVW(brA, 0);
  KBARRIER();

  for (int t = 0; t < KSTEPS - 1; t += 2) {
    STEP(t,     avA, avB, brB, brA, 0);  // compute t   (Bs[0]); A(t+1)->avB, B(t+2)->brA, conv B(t+1)->Bs[1]
    STEP(t + 1, avB, avA, brA, brB, 1);  // compute t+1 (Bs[1]); A(t+2)->avA, B(t+3)->brB, conv B(t+2)->Bs[0]
  }
  STEP(KSTEPS - 1, avA, avB, brB, brA, 0);  // ks 124 (even parity); guards false

#undef STEP
#undef KBARRIER
#undef MFMA_STEP
#undef CONVW
#undef LOADB
#undef LOADA

  // norm_all for this WG's 128 columns (pair-reduce the two half-rows)
  ssq += __shfl_xor(ssq, 1);
  if (bh == 0) norms[brow] = fmaxf(ssq, 1e-8f);

  // per-row approx top-8 over this WG's 128 columns (4 passes, one n-frag each)
  float tv[8]; int ti[8];
  #pragma unroll
  for (int q = 0; q < 8; ++q) { tv[q] = NEG_INF; ti[q] = 0; }

  #pragma unroll
  for (int p = 0; p < 4; ++p) {
    __syncthreads();   // p==0: full fence -> norms visible, acc final
    if (nh == (p >> 1)) {
      const int jj  = p & 1;
      const int ugc = n0 + 32 * p + lrow;
      const float inv = 1.0f / norms[32 * p + lrow];
      #pragma unroll
      for (int i = 0; i < 4; ++i)
        #pragma unroll
        for (int r = 0; r < 16; ++r) {
          int mrow = 128 * mh + 32 * i + (r & 3) + 8 * (r >> 2) + 4 * lhalf;  // verified C/D map
          sm.dump[mrow][lrow] = (ugc < N_USERS) ? acc[i][jj][r] * inv : NEG_INF;
        }
    }
    __syncthreads();
    for (int c = 0; c < 32; ++c) {
      float v = sm.dump[tid][c];
      int ci = n0 + 32 * p + c;
      if (v > tv[7]) {
        #pragma unroll
        for (int q = 0; q < 8; ++q) {
          bool gt = v > tv[q];
          float ov = tv[q]; int oi = ti[q];
          tv[q] = gt ? v : ov; ti[q] = gt ? ci : oi;
          v = gt ? ov : v;     ci = gt ? oi : ci;
        }
      }
    }
  }

  float2* dst = wstop + ((size_t)blockIdx.x * 256 + tid) * 8;   // b-row == tid
  #pragma unroll
  for (int q = 0; q < 8; ++q) dst[q] = make_float2(tv[q], __int_as_float(ti[q]));
}

// ---------------- Kernel 3: merge 391x8 candidates -> top-32 per row
__global__ __launch_bounds__(64) void merge_topk(
    const float2* __restrict__ wstop, int* __restrict__ cand) {
  const int b = blockIdx.x, l = threadIdx.x;
  float tv[8]; int ti[8];
  #pragma unroll
  for (int q = 0; q < 8; ++q) { tv[q] = NEG_INF; ti[q] = 0; }
  for (int c = l; c < NWG * 8; c += 64) {
    int wg = c >> 3, q = c & 7;
    float2 e = wstop[((size_t)wg * 256 + b) * 8 + q];
    float v = e.x; int ci = __float_as_int(e.y);
    #pragma unroll
    for (int q2 = 0; q2 < 8; ++q2) {
      bool gt = v > tv[q2];
      float ov = tv[q2]; int oi = ti[q2];
      tv[q2] = gt ? v : ov; ti[q2] = gt ? ci : oi;
      v = gt ? ov : v;      ci = gt ? oi : ci;
    }
  }
  __shared__ float sv[512];
  __shared__ int   si[512];
  #pragma unroll
  for (int q = 0; q < 8; ++q) { sv[l * 8 + q] = tv[q]; si[l * 8 + q] = ti[q]; }
  __syncthreads();
  if (l == 0) {
    float bv[32]; int bi[32];
    #pragma unroll
    for (int q = 0; q < 32; ++q) { bv[q] = NEG_INF; bi[q] = 0; }
    for (int n = 0; n < 512; ++n) {
      float v = sv[n];
      if (v > bv[31]) {
        int ci = si[n];
        #pragma unroll
        for (int q = 0; q < 32; ++q) {
          bool gt = v > bv[q];
          float ov = bv[q]; int oi = bi[q];
          bv[q] = gt ? v : ov; bi[q] = gt ? ci : oi;
          v = gt ? ov : v;     ci = gt ? oi : ci;
        }
      }
    }
    #pragma unroll
    for (int q = 0; q < 32; ++q) cand[b * 32 + q] = bi[q];
  }
}

// ---------------- Kernel 4: exact fp64 rescore of the 32 candidates per row
__global__ __launch_bounds__(64) void rescore(
    const float* __restrict__ F, const int* __restrict__ uids,
    const int* __restrict__ cand, double* __restrict__ simx) {
  const int pr = blockIdx.x;           // b*32 + q
  const int b  = pr >> 5;
  const int ci = cand[pr];
  const float* fa = F + (size_t)uids[b] * N_ITEMS;
  const float* fc = F + (size_t)ci * N_ITEMS;
  double dot = 0.0, ss = 0.0;
  for (int k = threadIdx.x * 4; k < N_ITEMS; k += 256) {
    float4 a = *(const float4*)(fa + k);
    float4 c = *(const float4*)(fc + k);
    dot += (double)a.x * c.x + (double)a.y * c.y + (double)a.z * c.z + (double)a.w * c.w;
    ss  += (double)c.x * c.x + (double)c.y * c.y + (double)c.z * c.z + (double)c.w * c.w;
  }
  #pragma unroll
  for (int off = 32; off > 0; off >>= 1) {
    dot += __shfl_down(dot, off);
    ss  += __shfl_down(ss, off);
  }
  // norm_users cancels in the weight normalization -> rank/weight by dot/norm_all only
  if (threadIdx.x == 0) simx[pr] = dot / fmax(ss, 1e-8);
}

// ---------------- Kernel 5: exact top-10, weights, weighted neighbor sum
__global__ __launch_bounds__(256) void finalize(
    const float* __restrict__ F, const int* __restrict__ cand,
    const double* __restrict__ simx, float* __restrict__ out) {
  const int b = blockIdx.x;
  __shared__ float wsh[10];
  __shared__ int   ish[10];
  if (threadIdx.x == 0) {
    double bv[10]; int bi[10];
    #pragma unroll
    for (int q = 0; q < 10; ++q) { bv[q] = -1.0e300; bi[q] = 0; }
    for (int n = 0; n < 32; ++n) {
      double v = simx[b * 32 + n];
      int ci = cand[b * 32 + n];
      #pragma unroll
      for (int q = 0; q < 10; ++q) {
        bool gt = v > bv[q];
        double ov = bv[q]; int oi = bi[q];
        bv[q] = gt ? v : ov; bi[q] = gt ? ci : oi;
        v = gt ? ov : v;     ci = gt ? oi : ci;
      }
    }
    double s = 0.0;
    #pragma unroll
    for (int q = 0; q < 10; ++q) s += bv[q];
    #pragma unroll
    for (int q = 0; q < 10; ++q) { wsh[q] = (float)(bv[q] / s); ish[q] = bi[q]; }
  }
  __syncthreads();
  float wr[10]; size_t ro[10];
  #pragma unroll
  for (int q = 0; q < 10; ++q) { wr[q] = wsh[q]; ro[q] = (size_t)ish[q] * N_ITEMS; }
  for (int i = threadIdx.x; i < N_ITEMS; i += 256) {
    float a = 0.f;
    #pragma unroll
    for (int q = 0; q < 10; ++q) a = fmaf(wr[q], F[ro[q] + i], a);
    out[b * N_ITEMS + i] = a;
  }
}

extern "C" void kernel_launch(void* const* d_in, const int* in_sizes, int n_in,
                              void* d_out, int out_size, void* d_ws, size_t ws_size,
                              hipStream_t stream) {
  const float* F    = (const float*)d_in[0];
  const int*   uids = (const int*)d_in[1];   // num_neighbors (d_in[2]) is fixed at 10
  float* out = (float*)d_out;
  char*  ws  = (char*)d_ws;

  // workspace layout (~8.6 MB total)
  unsigned short* apack = (unsigned short*)ws;                       // 2,048,000 B
  float2* wstop = (float2*)(ws + 2097152);                           // 6,406,144 B
  int*    cand  = (int*)(ws + 2097152 + 6406144);                    //    32,768 B
  double* simx  = (double*)(ws + 2097152 + 6406144 + 32768);         //    65,536 B

  prep_pack<<<dim3(BATCH), dim3(256), 0, stream>>>(F, uids, apack);
  gemm_topk<<<dim3(NWG),   dim3(256), 0, stream>>>(F, apack, wstop);
  merge_topk<<<dim3(BATCH), dim3(64), 0, stream>>>(wstop, cand);
  rescore<<<dim3(BATCH * 32), dim3(64), 0, stream>>>(F, uids, cand, simx);
  finalize<<<dim3(BATCH), dim3(256), 0, stream>>>(F, cand, simx, out);
}